// Round 13
// baseline (364.772 us; speedup 1.0000x reference)
//
#include <hip/hip_runtime.h>
#include <math.h>

// VariableSelectionNetwork — round 15.
// R14 banked (351us: vsn 230 + phase-C widening). Remaining controllable
// block: ctx_fused ~50us of PURE stream serialization in front of vsn.
// FIX: delete the dependency. sel[bidx] = softmax(LN(GRN(flat[bidx]))@Wsel)
// is a single-row GRN = 3 x 512-wide GEMVs (1.5 MFLOP) over the packed bf16
// weights (L2-resident, shared by all blocks). Each vsn block computes its
// own sel in a pre-loop phase (512 thr = 1 column each; LDS-shared vectors;
// ~4-5us/block) and writes its own 64 selw_out rows. Blocks sharing a bidx
// compute bitwise-identical sel -> disjoint writes, no sync, no dispatch-
// order assumptions. ctx_fused / gridbar / sel_ws / x1g / xg DELETED.
// Launches: pack_all + vsn_mfma only. vsn f-loop is R12-exact.

#define H 512
#define NF 4
#define MTOT 32768

typedef unsigned short u16;
typedef unsigned int u32;
typedef __attribute__((ext_vector_type(8))) short short8;   // 8 bf16 = 4 VGPRs
typedef __attribute__((ext_vector_type(4))) float f32x4;    // MFMA C/D
typedef __attribute__((ext_vector_type(4))) u32 u32x4;      // packed bf16 x8

__device__ __forceinline__ u16 f2bf(float x) {
  union { float f; u32 u; } v; v.f = x;
  return (u16)((v.u + 0x7fffu + ((v.u >> 16) & 1u)) >> 16);  // RNE
}
__device__ __forceinline__ float bf2f(u32 h16) {
  union { u32 u; float f; } v; v.u = h16 << 16;
  return v.f;
}
__device__ __forceinline__ float elu_f(float x) {
  return x > 0.0f ? x : (__expf(x) - 1.0f);
}
__device__ __forceinline__ float sigmoid_f(float x) {
  return __builtin_amdgcn_rcpf(1.0f + __expf(-x));
}
// packed 2x bf16 (lo->[15:0], hi->[31:16]), RNE — matches f2bf
__device__ __forceinline__ u32 cvtpk(float lo, float hi) {
  u32 r;
  asm("v_cvt_pk_bf16_f32 %0, %1, %2" : "=v"(r) : "v"(lo), "v"(hi));
  return r;
}
// butterfly-add over 16-lane groups via DPP (VALU pipe, no LDS)
template <int CTRL>
__device__ __forceinline__ float dppadd(float v) {
  int t = __builtin_amdgcn_update_dpp(0, __float_as_int(v), CTRL, 0xF, 0xF, true);
  return v + __int_as_float(t);
}
__device__ __forceinline__ float red16(float v) {
  v = dppadd<0xB1>(v);    // xor1
  v = dppadd<0x4E>(v);    // xor2
  v = dppadd<0x141>(v);   // row_half_mirror
  v = dppadd<0x140>(v);   // row_mirror
  return v;
}

// async global->LDS, 16B per lane; LDS dest = wave-uniform base + lane*16.
__device__ __forceinline__ void glld16(const void* g, void* l) {
  __builtin_amdgcn_global_load_lds(
      (const __attribute__((address_space(1))) u32*)(unsigned long long)(uintptr_t)g,
      (__attribute__((address_space(3))) u32*)(u32)(uintptr_t)l, 16, 0, 0);
}

#define MFMA16(a, b, c) __builtin_amdgcn_mfma_f32_16x16x32_bf16((a), (b), (c), 0, 0, 0)

struct TileCtx {
  int tid, wid, lane, quad, col;
};

// ---------------- pack_all: all 11 matrices. grid 1408. --------------------
// mats 0-3 W2[f] chunk, 4-7 Wg[f] chunk, 8 W1c slab, 9 W2c slab, 10 Wgc chunk.
__global__ __launch_bounds__(256)
void pack_all(const float* __restrict__ W2, const float* __restrict__ Wg,
              const float* __restrict__ W1c, const float* __restrict__ W2c,
              const float* __restrict__ Wgc,
              u16* __restrict__ W2p, u16* __restrict__ Wgp, u16* __restrict__ Cp) {
  int g = blockIdx.x * 256 + threadIdx.x;       // 0 .. 11*32768-1
  int r = g & 32767; int mat = g >> 15;
  if (mat >= 11) return;
  const float* src; u16* dst;
  if (mat < 4)      { src = W2 + (size_t)mat * 262144;       dst = W2p + (size_t)mat * 262144; }
  else if (mat < 8) { src = Wg + (size_t)(mat - 4) * 262144; dst = Wgp + (size_t)(mat - 4) * 262144; }
  else              { src = (mat == 8 ? W1c : (mat == 9 ? W2c : Wgc));
                      dst = Cp + (size_t)(mat - 8) * 262144; }
  dst += (size_t)r * 8;
  int lane = r & 63;
  int n, k0;
  if (mat == 8 || mat == 9) {   // slab layout
    int nb = r >> 12, kk = (r >> 8) & 15, ntg = (r >> 6) & 3;
    n  = nb * 64 + ntg * 16 + (lane & 15);
    k0 = kk * 32 + (lane >> 4) * 8;
  } else {                      // chunk layout
    int nt = (r >> 6) & 31, kk = (r >> 11) & 15;
    n  = nt * 16 + (lane & 15);
    k0 = kk * 32 + (lane >> 4) * 8;
  }
  short8 pk;
  #pragma unroll
  for (int j = 0; j < 8; ++j) pk[j] = (short)f2bf(src[(size_t)(k0 + j) * H + n]);
  *(short8*)dst = pk;
}

// ======================= GEMV helpers (local sel phase) =======================
// thread owns column n; vec is fp32[512] in LDS (broadcast reads, no conflict).

// slab layout (Cp mats 8,9): group(k,n) at (n>>6)*32768 + ((n>>4)&3)*512 +
// (n&15)*8 + (k>>5)*2048 + ((k>>3)&3)*128, covering k..k+7.
__device__ __forceinline__ float gemv512_slab(const u16* __restrict__ W,
                                              const float* __restrict__ vec, int n) {
  const u16* base = W + (size_t)(n >> 6) * 32768 + ((n >> 4) & 3) * 512 + (n & 15) * 8;
  float acc = 0.f;
  #pragma unroll 4
  for (int kg = 0; kg < 64; ++kg) {
    short8 w = *(const short8*)(base + (kg >> 2) * 2048 + (kg & 3) * 128);
    float4 v0 = *(const float4*)&vec[kg * 8];
    float4 v1 = *(const float4*)&vec[kg * 8 + 4];
    acc = fmaf(v0.x, bf2f((u16)w[0]), acc);
    acc = fmaf(v0.y, bf2f((u16)w[1]), acc);
    acc = fmaf(v0.z, bf2f((u16)w[2]), acc);
    acc = fmaf(v0.w, bf2f((u16)w[3]), acc);
    acc = fmaf(v1.x, bf2f((u16)w[4]), acc);
    acc = fmaf(v1.y, bf2f((u16)w[5]), acc);
    acc = fmaf(v1.z, bf2f((u16)w[6]), acc);
    acc = fmaf(v1.w, bf2f((u16)w[7]), acc);
  }
  return acc;
}

// chunk layout (Cp mat 10): group(k,n) at (n>>4)*512 + (n&15)*8 +
// (k>>5)*16384 + ((k>>3)&3)*128.
__device__ __forceinline__ float gemv512_chunk(const u16* __restrict__ W,
                                               const float* __restrict__ vec, int n) {
  const u16* base = W + (size_t)(n >> 4) * 512 + (n & 15) * 8;
  float acc = 0.f;
  #pragma unroll 4
  for (int kg = 0; kg < 64; ++kg) {
    short8 w = *(const short8*)(base + (kg >> 2) * 16384 + (kg & 3) * 128);
    float4 v0 = *(const float4*)&vec[kg * 8];
    float4 v1 = *(const float4*)&vec[kg * 8 + 4];
    acc = fmaf(v0.x, bf2f((u16)w[0]), acc);
    acc = fmaf(v0.y, bf2f((u16)w[1]), acc);
    acc = fmaf(v0.z, bf2f((u16)w[2]), acc);
    acc = fmaf(v0.w, bf2f((u16)w[3]), acc);
    acc = fmaf(v1.x, bf2f((u16)w[4]), acc);
    acc = fmaf(v1.y, bf2f((u16)w[5]), acc);
    acc = fmaf(v1.z, bf2f((u16)w[6]), acc);
    acc = fmaf(v1.w, bf2f((u16)w[7]), acc);
  }
  return acc;
}

// ======================= vsn machinery (R12-exact) =======================

// wave-private staging: wave wid's 4KB slice (cols wid*64..+63) of a 32KB chunk.
__device__ __forceinline__ void stage_slice(int wid, int lane, const u16* chunk, u16* dstbuf) {
  const u16* src = chunk + wid * 2048 + lane * 8;
  u16* dst = dstbuf + lane * 8;
  glld16(src,        dst);
  glld16(src + 512,  dst + 512);
  glld16(src + 1024, dst + 1024);
  glld16(src + 1536, dst + 1536);
}

// barrier-free K-loop: per-wave double-buffered B slices, per-wave vmcnt.
__device__ __forceinline__ void gemm_kloop_nb(const TileCtx& c, const u16* Wp,
                                              const u16* sA, u16* sBw,
                                              f32x4 acc[4][4]) {
  #pragma unroll 1
  for (int kk = 0; kk < 16; ++kk) {
    if (kk < 15) {
      stage_slice(c.wid, c.lane, Wp + (kk + 1) * 16384, sBw + ((kk + 1) & 1) * 2048);
      asm volatile("s_waitcnt vmcnt(4)" ::: "memory");   // chunk kk's 4 landed (own wave)
    } else {
      asm volatile("s_waitcnt vmcnt(0)" ::: "memory");
    }
    __builtin_amdgcn_sched_barrier(0);
    const u16* bp = sBw + (kk & 1) * 2048 + c.lane * 8;
    short8 bb[4];
    #pragma unroll
    for (int nt = 0; nt < 4; ++nt) bb[nt] = *(const short8*)(bp + nt * 512);
    const int kq = kk * 4 + c.quad;
    const int s0 = (kq ^ (c.col & 7)) * 8;
    __builtin_amdgcn_s_setprio(1);
    #pragma unroll
    for (int mt = 0; mt < 4; ++mt) {
      short8 a = *(const short8*)&sA[(mt * 16 + c.col) * 512 + s0];
      #pragma unroll
      for (int nt = 0; nt < 4; ++nt)
        acc[mt][nt] = MFMA16(a, bb[nt], acc[mt][nt]);
    }
    __builtin_amdgcn_s_setprio(0);
  }
}

// store one C-layout value-pair set into sA[m][k] bf16 via lane-pair exchange.
__device__ __forceinline__ void store_x2_pair_n(const TileCtx& c, u16* sA,
                                                int mt, int n, u32 o01, u32 o23) {
  const bool even = (c.lane & 1) == 0;
  const u32 send = even ? o23 : o01;
  const u32 recv = (u32)__builtin_amdgcn_update_dpp(0, (int)send, 0xB1, 0xF, 0xF, true);
  const u32 hi = even ? recv : o23;
  const u32 lo = even ? o01 : recv;
  const u32 dlo = __builtin_amdgcn_perm(hi, lo, 0x05040100u);
  const u32 dhi = __builtin_amdgcn_perm(hi, lo, 0x07060302u);
  const int np = n & ~1;
  const int mA = mt * 16 + c.quad * 4 + (even ? 0 : 2);
  const int iA = mA * 512 + ((((np >> 3) ^ (mA & 7)) << 3) + (np & 7));
  const int mB = mA + 1;
  const int iB = mB * 512 + ((((np >> 3) ^ (mB & 7)) << 3) + (np & 7));
  *(u32*)&sA[iA] = dlo;
  *(u32*)&sA[iB] = dhi;
}

// LN over 512 cols for 64 rows, 8-wave. Partials stride 20 floats.
__device__ __forceinline__ void ln_reduce8(const TileCtx& c, float* sRedF,
                                           f32x4 acc[4][4]) {
  #pragma unroll
  for (int mt = 0; mt < 4; ++mt) {
    float rs[4], rq[4];
    #pragma unroll
    for (int reg = 0; reg < 4; ++reg) {
      rs[reg] = 0.f; rq[reg] = 0.f;
      #pragma unroll
      for (int nt = 0; nt < 4; ++nt) {
        const float gt = acc[mt][nt][reg];
        rs[reg] += gt; rq[reg] += gt * gt;
      }
      rs[reg] = red16(rs[reg]);
      rq[reg] = red16(rq[reg]);
    }
    if (c.col == 0) {
      #pragma unroll
      for (int reg = 0; reg < 4; ++reg) {
        const int m = mt * 16 + c.quad * 4 + reg;
        float2 sq; sq.x = rs[reg]; sq.y = rq[reg];
        *(float2*)&sRedF[m * 20 + c.wid * 2] = sq;
      }
    }
  }
  __syncthreads();
  if (c.tid < 64) {
    const int row = c.tid;
    float s = 0.f, q = 0.f;
    #pragma unroll
    for (int jj = 0; jj < 4; ++jj) {
      float4 v = *(float4*)&sRedF[row * 20 + jj * 4];
      s += v.x + v.z; q += v.y + v.w;
    }
    const float mu = s * (1.0f / H);
    const float rstd = rsqrtf(q * (1.0f / H) - mu * mu + 1e-3f);
    float2 mr; mr.x = mu; mr.y = rstd;
    *(float2*)&sRedF[1280 + row * 2] = mr;
  }
  __syncthreads();
}

// ---------------- vsn_mfma: local sel + per-variable GRNs + selection ----------------
__global__ __launch_bounds__(512, 2)
void vsn_mfma(const float* __restrict__ in,     // [MTOT, F] == flat [B, 512]
              const float* __restrict__ w1, const float* __restrict__ b1,
              const float* __restrict__ b2, const float* __restrict__ bg,
              const float* __restrict__ gamma, const float* __restrict__ beta,
              const u16* __restrict__ W2p, const u16* __restrict__ Wgp,
              const u16* __restrict__ Cp,      // W1c slab | W2c slab | Wgc chunk
              const float* __restrict__ b1c, const float* __restrict__ b2c,
              const float* __restrict__ bgc,
              const float* __restrict__ gamma_c, const float* __restrict__ beta_c,
              const float* __restrict__ Wsel, const float* __restrict__ bsel,
              float* __restrict__ out,         // [MTOT, H]
              float* __restrict__ selw_out)    // [B, T, 1, F] == [MTOT, F]
{
  __shared__ __align__(16) u16 smem[65552];    // 128KB + 32B sel tail
  u16* const sA  = smem;              // [64][512] bf16 XOR-swizzled, 64 KB
  u16* const sB  = smem + 32768;      // 8 waves x 8KB double-buffer slices
  float* const sRedF = (float*)smem;  // LN partials overlay sA
  float* const sSelP = (float*)&smem[65536];   // persistent sel[4]

  TileCtx c;
  c.tid = threadIdx.x; c.wid = c.tid >> 6; c.lane = c.tid & 63;
  c.quad = c.lane >> 4; c.col = c.lane & 15;
  u16* const sBw = sB + c.wid * 4096;  // this wave's 8KB (2 x 2048 u16)
  const int row0 = blockIdx.x * 64;
  const int bidx = row0 >> 7;

  // ======== local sel phase (replaces ctx kernel; LDS scratch in sB area) ====
  {
    float* const sF  = (float*)(smem + 32768);   // fp32[512] flat
    float* const sV1 = sF + 512;                 // fp32[512] x1
    float* const sV2 = sV1 + 512;                // fp32[512] x
    float* const sP  = sV2 + 512;                // partials / mu / z
    const int n = c.tid;
    const float flat_n = in[(size_t)bidx * 512 + n];
    sF[n] = flat_n;
    __syncthreads();
    const float x1 = elu_f(gemv512_slab(Cp, sF, n) + b1c[n]);
    sV1[n] = x1;
    __syncthreads();
    const float xv = gemv512_slab(Cp + 262144, sV1, n) + b2c[n];
    sV2[n] = xv;
    __syncthreads();
    const float gp = gemv512_chunk(Cp + 524288, sV2, n) + bgc[n];
    const float gv = sigmoid_f(gp);
    const float gated = gv * xv + (1.0f - gv) * flat_n;
    {
      float s = red16(gated), q = red16(gated * gated);
      if ((c.lane & 15) == 0) { sP[c.tid >> 4] = s; sP[32 + (c.tid >> 4)] = q; }
    }
    __syncthreads();
    if (c.tid == 0) {
      float ss = 0.f, qq = 0.f;
      #pragma unroll
      for (int i = 0; i < 32; ++i) { ss += sP[i]; qq += sP[32 + i]; }
      const float mu = ss * (1.0f / H);
      const float rstd = rsqrtf(qq * (1.0f / H) - mu * mu + 1e-3f);
      sP[64] = mu; sP[65] = rstd;
    }
    __syncthreads();
    const float ctxv = gamma_c[n] * ((gated - sP[64]) * sP[65]) + beta_c[n];
    {
      float4 ws = *(const float4*)&Wsel[n * NF];
      float z0 = red16(ctxv * ws.x), z1 = red16(ctxv * ws.y);
      float z2 = red16(ctxv * ws.z), z3 = red16(ctxv * ws.w);
      if ((c.lane & 15) == 0) {
        float4 zz; zz.x = z0; zz.y = z1; zz.z = z2; zz.w = z3;
        *(float4*)&sP[68 + (c.tid >> 4) * 4] = zz;
      }
    }
    __syncthreads();
    if (c.tid == 0) {
      float z0 = bsel[0], z1 = bsel[1], z2 = bsel[2], z3 = bsel[3];
      #pragma unroll
      for (int i = 0; i < 32; ++i) {
        float4 zz = *(float4*)&sP[68 + i * 4];
        z0 += zz.x; z1 += zz.y; z2 += zz.z; z3 += zz.w;
      }
      const float mx = fmaxf(fmaxf(z0, z1), fmaxf(z2, z3));
      const float e0 = __expf(z0-mx), e1 = __expf(z1-mx);
      const float e2 = __expf(z2-mx), e3 = __expf(z3-mx);
      const float inv = __builtin_amdgcn_rcpf(e0 + e1 + e2 + e3);
      sSelP[0] = e0*inv; sSelP[1] = e1*inv; sSelP[2] = e2*inv; sSelP[3] = e3*inv;
    }
    __syncthreads();   // sel ready; all sF/sV/sP reads done -> sB reusable
    if (c.tid < 64) {
      float4 v; v.x = sSelP[0]; v.y = sSelP[1]; v.z = sSelP[2]; v.w = sSelP[3];
      *(float4*)&selw_out[(size_t)(row0 + c.tid) * NF] = v;
    }
  }

  f32x4 outacc[4][4];
  #pragma unroll
  for (int mt = 0; mt < 4; ++mt)
    #pragma unroll
    for (int nt = 0; nt < 4; ++nt) outacc[mt][nt] = (f32x4){0,0,0,0};

  // stage f=0 GEMM1 chunk0 slice (overlapped by first A1 phase)
  stage_slice(c.wid, c.lane, W2p, sBw);

  #pragma unroll 1
  for (int f = 0; f < NF; ++f) {
    const u16* W2f = W2p + (size_t)f * 262144;
    const u16* Wgf = Wgp + (size_t)f * 262144;

    // A1: sA[m][k] = bf16(elu(v[m]*w1[k] + b1[k])), rotated k-group order
    {
      const int m  = c.tid >> 3;
      const int kb = (c.tid & 7) * 64;
      const float v = in[(size_t)(row0 + m) * NF + f];
      const float* w1f = w1 + f * H;
      const float* b1f = b1 + f * H;
      #pragma unroll
      for (int gg = 0; gg < 8; ++gg) {
        const int ge = (gg + (c.tid & 7)) & 7;
        const int k = kb + ge * 8;
        float4 wv0 = *(const float4*)&w1f[k];
        float4 wv1 = *(const float4*)&w1f[k + 4];
        float4 bv0 = *(const float4*)&b1f[k];
        float4 bv1 = *(const float4*)&b1f[k + 4];
        u32x4 pk4;
        pk4.x = cvtpk(elu_f(fmaf(v, wv0.x, bv0.x)), elu_f(fmaf(v, wv0.y, bv0.y)));
        pk4.y = cvtpk(elu_f(fmaf(v, wv0.z, bv0.z)), elu_f(fmaf(v, wv0.w, bv0.w)));
        pk4.z = cvtpk(elu_f(fmaf(v, wv1.x, bv1.x)), elu_f(fmaf(v, wv1.y, bv1.y)));
        pk4.w = cvtpk(elu_f(fmaf(v, wv1.z, bv1.z)), elu_f(fmaf(v, wv1.w, bv1.w)));
        const int grp = (k >> 3) ^ (m & 7);
        *(u32x4*)&sA[m * 512 + grp * 8] = pk4;
      }
    }
    __syncthreads();   // A1 visible; chunk0 slices drained (vmcnt 0)

    f32x4 acc[4][4];
    #pragma unroll
    for (int mt = 0; mt < 4; ++mt)
      #pragma unroll
      for (int nt = 0; nt < 4; ++nt) acc[mt][nt] = (f32x4){0,0,0,0};

    // GEMM1: barrier-free, per-wave staged
    gemm_kloop_nb(c, W2f, sA, sBw, acc);
    __syncthreads();   // all waves done reading sA (x1) before x2 overwrite

    // prefetch GEMM2 chunk0 slice (covered by epilogue; drained at next bar)
    stage_slice(c.wid, c.lane, Wgf, sBw);

    // epilogue1: x2 = acc + b2 -> packed regs + sA
    u32 x2p[4][4][2];
    {
      float bv[4];
      #pragma unroll
      for (int nt = 0; nt < 4; ++nt) bv[nt] = b2[f * H + c.wid * 64 + nt * 16 + c.col];
      #pragma unroll
      for (int mt = 0; mt < 4; ++mt)
        #pragma unroll
        for (int nt = 0; nt < 4; ++nt) {
          const u32 o01 = cvtpk(acc[mt][nt][0] + bv[nt], acc[mt][nt][1] + bv[nt]);
          const u32 o23 = cvtpk(acc[mt][nt][2] + bv[nt], acc[mt][nt][3] + bv[nt]);
          x2p[mt][nt][0] = o01; x2p[mt][nt][1] = o23;
          store_x2_pair_n(c, sA, mt, c.wid * 64 + nt * 16 + c.col, o01, o23);
        }
    }
    __syncthreads();   // x2 visible; chunk0 drained

    // GEMM2: barrier-free
    #pragma unroll
    for (int mt = 0; mt < 4; ++mt)
      #pragma unroll
      for (int nt = 0; nt < 4; ++nt) acc[mt][nt] = (f32x4){0,0,0,0};
    gemm_kloop_nb(c, Wgf, sA, sBw, acc);

    // gate (reg-only: acc, x2p, in, bv)
    {
      const float selw = sSelP[f];
      float bv[4];
      #pragma unroll
      for (int nt = 0; nt < 4; ++nt) bv[nt] = bg[f * H + c.wid * 64 + nt * 16 + c.col];
      #pragma unroll
      for (int mt = 0; mt < 4; ++mt) {
        float vr[4];
        #pragma unroll
        for (int reg = 0; reg < 4; ++reg)
          vr[reg] = in[(size_t)(row0 + mt * 16 + c.quad * 4 + reg) * NF + f];
        #pragma unroll
        for (int nt = 0; nt < 4; ++nt)
          #pragma unroll
          for (int reg = 0; reg < 4; ++reg) {
            const u32 w = x2p[mt][nt][reg >> 1];
            const float x2v = bf2f((reg & 1) ? (w >> 16) : (w & 0xffffu));
            const float gv = sigmoid_f(acc[mt][nt][reg] + bv[nt]);
            acc[mt][nt][reg] = gv * x2v + (1.0f - gv) * vr[reg];
          }
      }
      __syncthreads();   // all waves done reading sA (x2) before sRedF overlay
      ln_reduce8(c, sRedF, acc);
      float gm[4], bt[4];
      #pragma unroll
      for (int nt = 0; nt < 4; ++nt) {
        const int n = f * H + c.wid * 64 + nt * 16 + c.col;
        gm[nt] = gamma[n]; bt[nt] = beta[n];
      }
      #pragma unroll
      for (int mt = 0; mt < 4; ++mt)
        #pragma unroll
        for (int reg = 0; reg < 4; ++reg) {
          const int m = mt * 16 + c.quad * 4 + reg;
          float2 mr = *(float2*)&sRedF[1280 + m * 2];
          #pragma unroll
          for (int nt = 0; nt < 4; ++nt) {
            const float tv = gm[nt] * ((acc[mt][nt][reg] - mr.x) * mr.y) + bt[nt];
            outacc[mt][nt][reg] = fmaf(selw, tv, outacc[mt][nt][reg]);
          }
        }
      // prefetch next f's GEMM1 chunk0 slice (drained by the barrier below)
      if (f < NF - 1)
        stage_slice(c.wid, c.lane, W2p + (size_t)(f + 1) * 262144, sBw);
      __syncthreads();   // sRedF reads done before next f's A1 overwrites sA
    }
  }

  // store selected [MTOT, H]
  #pragma unroll
  for (int mt = 0; mt < 4; ++mt)
    #pragma unroll
    for (int reg = 0; reg < 4; ++reg) {
      const int m = row0 + mt * 16 + c.quad * 4 + reg;
      #pragma unroll
      for (int nt = 0; nt < 4; ++nt)
        out[(size_t)m * H + c.wid * 64 + nt * 16 + c.col] = outacc[mt][nt][reg];
    }
}

extern "C" void kernel_launch(void* const* d_in, const int* in_sizes, int n_in,
                              void* d_out, int out_size, void* d_ws, size_t ws_size,
                              hipStream_t stream) {
  const float* in_     = (const float*)d_in[0];
  const float* W1c     = (const float*)d_in[1];
  const float* b1c     = (const float*)d_in[2];
  const float* W2c     = (const float*)d_in[3];
  const float* b2c     = (const float*)d_in[4];
  const float* Wgc     = (const float*)d_in[5];
  const float* bgc     = (const float*)d_in[6];
  const float* gamma_c = (const float*)d_in[7];
  const float* beta_c  = (const float*)d_in[8];
  const float* Wsel    = (const float*)d_in[9];
  const float* bsel    = (const float*)d_in[10];
  const float* w1      = (const float*)d_in[11];
  const float* b1v     = (const float*)d_in[12];
  const float* W2      = (const float*)d_in[13];
  const float* b2v     = (const float*)d_in[14];
  const float* Wg      = (const float*)d_in[15];
  const float* bgv     = (const float*)d_in[16];
  const float* gma     = (const float*)d_in[17];
  const float* bta     = (const float*)d_in[18];

  float* out_sel = (float*)d_out;                      // [MTOT, H]
  float* out_w   = (float*)d_out + (size_t)MTOT * H;   // [B, T, 1, F]

  u16*   W2p    = (u16*)d_ws;                          // 2 MB
  u16*   Wgp    = W2p + (size_t)NF * H * H;            // 2 MB
  u16*   Cp     = Wgp + (size_t)NF * H * H;            // 1.5 MB (W1c|W2c|Wgc)

  hipLaunchKernelGGL(pack_all, dim3(1408), dim3(256), 0, stream,
                     W2, Wg, W1c, W2c, Wgc, W2p, Wgp, Cp);
  hipLaunchKernelGGL(vsn_mfma, dim3(MTOT / 64), dim3(512), 0, stream,
                     in_, w1, b1v, b2v, bgv, gma, bta, W2p, Wgp,
                     Cp, b1c, b2c, bgc, gamma_c, beta_c, Wsel, bsel,
                     out_sel, out_w);
}